// Round 11
// baseline (42.294 us; speedup 1.0000x reference)
//
#include <hip/hip_runtime.h>
#include <math.h>

#define B_   64
#define C_   768
#define HW_  1024          // 32*32
#define NCLS 100
#define E_   16
#define K_   2
#define FAN  (C_ + NCLS)   // 868

typedef float vfloat4 __attribute__((ext_vector_type(4)));

// Pool: one wave per FOUR (b,c) rows -> 16 independent float4 loads/thread
// in flight before any dependent ALU (MLP probe: 2x deeper than R5).
// 49152 rows / 4 = 12288 waves -> 3072 blocks.
__global__ __launch_bounds__(256) void pool_kernel(const float* __restrict__ x,
                                                   float* __restrict__ pooled) {
    const int wave = (blockIdx.x * 256 + threadIdx.x) >> 6;   // 0..12287
    const int lane = threadIdx.x & 63;
    const int r0   = wave * 4;                                // first of 4 rows

    vfloat4 v[4][4];
    #pragma unroll
    for (int r = 0; r < 4; ++r) {
        const vfloat4* p = reinterpret_cast<const vfloat4*>(x + (size_t)(r0 + r) * HW_);
        #pragma unroll
        for (int c = 0; c < 4; ++c) v[r][c] = p[lane + 64 * c];
    }

    float s[4];
    #pragma unroll
    for (int r = 0; r < 4; ++r) {
        s[r] = (v[r][0].x + v[r][0].y + v[r][0].z + v[r][0].w)
             + (v[r][1].x + v[r][1].y + v[r][1].z + v[r][1].w)
             + (v[r][2].x + v[r][2].y + v[r][2].z + v[r][2].w)
             + (v[r][3].x + v[r][3].y + v[r][3].z + v[r][3].w);
    }

    #pragma unroll
    for (int off = 32; off > 0; off >>= 1) {
        #pragma unroll
        for (int r = 0; r < 4; ++r) s[r] += __shfl_down(s[r], off);
    }
    if (lane == 0) {
        #pragma unroll
        for (int r = 0; r < 4; ++r) pooled[r0 + r] = s[r] * (1.0f / 1024.0f);
    }
}

// Router: one block per batch. Each wave computes its 4 experts concurrently
// (4 accumulators, one LDS read feeds 4 FMAs, 4 W-streams in flight).
__global__ __launch_bounds__(256) void router_kernel(const float* __restrict__ pooled,
                                                     const float* __restrict__ task_cls,
                                                     const float* __restrict__ Wm,
                                                     const float* __restrict__ bias,
                                                     float* __restrict__ out) {
    const int b    = blockIdx.x;
    const int tid  = threadIdx.x;
    const int lane = tid & 63;
    const int wav  = tid >> 6;

    __shared__ float fused[FAN];
    __shared__ float logits_s[E_];
    __shared__ int   sel_s[K_];

    // pooled image features -> fused[0..767] (float4 staging, 192 vec loads)
    if (tid < 192) {
        reinterpret_cast<vfloat4*>(fused)[tid] =
            reinterpret_cast<const vfloat4*>(pooled + b * C_)[tid];
    }

    // softmax(task_cls[b]) -> fused[768..867]; wave 1 handles all 100 elems
    if (wav == 1) {
        float v1 = task_cls[b * NCLS + lane];
        bool has2 = (lane + 64) < NCLS;
        float v2 = has2 ? task_cls[b * NCLS + lane + 64] : -INFINITY;
        float m = fmaxf(v1, v2);
        #pragma unroll
        for (int off = 32; off > 0; off >>= 1) m = fmaxf(m, __shfl_down(m, off));
        m = __shfl(m, 0);
        float e1 = __expf(v1 - m);
        float e2 = has2 ? __expf(v2 - m) : 0.0f;
        float sm = e1 + e2;
        #pragma unroll
        for (int off = 32; off > 0; off >>= 1) sm += __shfl_down(sm, off);
        sm = __shfl(sm, 0);
        float inv = 1.0f / sm;
        fused[C_ + lane] = e1 * inv;
        if (has2) fused[C_ + lane + 64] = e2 * inv;
    }
    __syncthreads();

    // 16 expert dots: wave w owns experts 4w..4w+3, computed concurrently
    {
        const int e0 = wav * 4;
        const float* w0 = Wm + (size_t)(e0 + 0) * FAN;
        const float* w1 = Wm + (size_t)(e0 + 1) * FAN;
        const float* w2 = Wm + (size_t)(e0 + 2) * FAN;
        const float* w3 = Wm + (size_t)(e0 + 3) * FAN;
        float acc0 = 0.0f, acc1 = 0.0f, acc2 = 0.0f, acc3 = 0.0f;
        for (int j = lane; j < FAN; j += 64) {
            float f = fused[j];
            acc0 += f * w0[j];
            acc1 += f * w1[j];
            acc2 += f * w2[j];
            acc3 += f * w3[j];
        }
        #pragma unroll
        for (int off = 32; off > 0; off >>= 1) {
            acc0 += __shfl_down(acc0, off);
            acc1 += __shfl_down(acc1, off);
            acc2 += __shfl_down(acc2, off);
            acc3 += __shfl_down(acc3, off);
        }
        if (lane == 0) {
            float l0 = acc0 + bias[e0 + 0];
            float l1 = acc1 + bias[e0 + 1];
            float l2 = acc2 + bias[e0 + 2];
            float l3 = acc3 + bias[e0 + 3];
            logits_s[e0 + 0] = l0;  out[b * E_ + e0 + 0] = l0;  // router_logits @0
            logits_s[e0 + 1] = l1;  out[b * E_ + e0 + 1] = l1;
            logits_s[e0 + 2] = l2;  out[b * E_ + e0 + 2] = l2;
            logits_s[e0 + 3] = l3;  out[b * E_ + e0 + 3] = l3;
        }
    }
    __syncthreads();

    // top-2 (strict > keeps lowest index on ties, matching lax.top_k)
    if (tid == 0) {
        float m1 = -INFINITY, m2 = -INFINITY;
        int i1 = 0, i2 = 0;
        #pragma unroll
        for (int e = 0; e < E_; ++e) {
            float v = logits_s[e];
            if (v > m1) { m2 = m1; i2 = i1; m1 = v; i1 = e; }
            else if (v > m2) { m2 = v; i2 = e; }
        }
        float r = expf(m2 - m1);
        float w0 = 1.0f / (1.0f + r);
        float w1 = r * w0;
        out[1024 + b * K_ + 0] = w0;              // router_weights [B,K] @ 1024
        out[1024 + b * K_ + 1] = w1;
        out[1152 + b * K_ + 0] = (float)i1;       // selected_experts [B,K] @ 1152
        out[1152 + b * K_ + 1] = (float)i2;
        sel_s[0] = i1; sel_s[1] = i2;
    }
    __syncthreads();

    // expert_mask [E,K,B] @ 1280 : flat e*K*B + k*B + b
    if (tid < E_ * K_) {
        int e = tid >> 1;
        int k = tid & 1;
        out[1280 + e * (K_ * B_) + k * B_ + b] = (sel_s[k] == e) ? 1.0f : 0.0f;
    }
}

extern "C" void kernel_launch(void* const* d_in, const int* in_sizes, int n_in,
                              void* d_out, int out_size, void* d_ws, size_t ws_size,
                              hipStream_t stream) {
    const float* hidden   = (const float*)d_in[0];  // [64,768,32,32]
    const float* task_cls = (const float*)d_in[1];  // [64,100]
    const float* Wm       = (const float*)d_in[2];  // [16,868]
    const float* bias     = (const float*)d_in[3];  // [16]
    float* out = (float*)d_out;
    float* pooled = (float*)d_ws;                   // B*C floats = 192 KiB

    // 49152 rows, 4 rows per wave, 4 waves per block -> 3072 blocks
    pool_kernel<<<3072, 256, 0, stream>>>(hidden, pooled);
    router_kernel<<<B_, 256, 0, stream>>>(pooled, task_cls, Wm, bias, out);
}

// Round 12
// 41.010 us; speedup vs baseline: 1.0313x; 1.0313x over previous
//
#include <hip/hip_runtime.h>
#include <math.h>

#define B_   64
#define C_   768
#define HW_  1024          // 32*32
#define NCLS 100
#define E_   16
#define K_   2
#define FAN  (C_ + NCLS)   // 868

typedef float vfloat4 __attribute__((ext_vector_type(4)));

// FINAL (best measured, R10 = 41.1 us):
//   pool: one wave per TWO rows, 8 independent float4 loads/thread.
//     MLP-insensitive (4/8/16 loads-in-flight all ~equal) -> BW-capped.
//   router: 64 blocks, each wave computes its 4 experts CONCURRENTLY
//     (this fix was worth 12.5 us: 53.5 -> 41.1).
//   Fusion variants (R3/R6/R7/R8) all lose: device-scope fences cause bulk
//   L2 writeback/invalidate; kernel boundary is the cheapest sync.
__global__ __launch_bounds__(256) void pool_kernel(const float* __restrict__ x,
                                                   float* __restrict__ pooled) {
    const int wave = (blockIdx.x * 256 + threadIdx.x) >> 6;   // 0..24575
    const int lane = threadIdx.x & 63;
    const int r0   = wave * 2;                                // first of 2 rows

    const vfloat4* p0 = reinterpret_cast<const vfloat4*>(x + (size_t)r0 * HW_);
    const vfloat4* p1 = reinterpret_cast<const vfloat4*>(x + (size_t)(r0 + 1) * HW_);
    vfloat4 a0 = p0[lane];
    vfloat4 a1 = p0[lane + 64];
    vfloat4 a2 = p0[lane + 128];
    vfloat4 a3 = p0[lane + 192];
    vfloat4 b0 = p1[lane];
    vfloat4 b1 = p1[lane + 64];
    vfloat4 b2 = p1[lane + 128];
    vfloat4 b3 = p1[lane + 192];

    float s0 = (a0.x + a0.y + a0.z + a0.w) + (a1.x + a1.y + a1.z + a1.w)
             + (a2.x + a2.y + a2.z + a2.w) + (a3.x + a3.y + a3.z + a3.w);
    float s1 = (b0.x + b0.y + b0.z + b0.w) + (b1.x + b1.y + b1.z + b1.w)
             + (b2.x + b2.y + b2.z + b2.w) + (b3.x + b3.y + b3.z + b3.w);

    #pragma unroll
    for (int off = 32; off > 0; off >>= 1) {
        s0 += __shfl_down(s0, off);
        s1 += __shfl_down(s1, off);
    }
    if (lane == 0) {
        pooled[r0]     = s0 * (1.0f / 1024.0f);
        pooled[r0 + 1] = s1 * (1.0f / 1024.0f);
    }
}

// Router: one block per batch. Each wave computes its 4 experts concurrently
// (4 accumulators, one LDS read feeds 4 FMAs, 4 W-streams in flight).
__global__ __launch_bounds__(256) void router_kernel(const float* __restrict__ pooled,
                                                     const float* __restrict__ task_cls,
                                                     const float* __restrict__ Wm,
                                                     const float* __restrict__ bias,
                                                     float* __restrict__ out) {
    const int b    = blockIdx.x;
    const int tid  = threadIdx.x;
    const int lane = tid & 63;
    const int wav  = tid >> 6;

    __shared__ float fused[FAN];
    __shared__ float logits_s[E_];
    __shared__ int   sel_s[K_];

    // pooled image features -> fused[0..767] (float4 staging, 192 vec loads)
    if (tid < 192) {
        reinterpret_cast<vfloat4*>(fused)[tid] =
            reinterpret_cast<const vfloat4*>(pooled + b * C_)[tid];
    }

    // softmax(task_cls[b]) -> fused[768..867]; wave 1 handles all 100 elems
    if (wav == 1) {
        float v1 = task_cls[b * NCLS + lane];
        bool has2 = (lane + 64) < NCLS;
        float v2 = has2 ? task_cls[b * NCLS + lane + 64] : -INFINITY;
        float m = fmaxf(v1, v2);
        #pragma unroll
        for (int off = 32; off > 0; off >>= 1) m = fmaxf(m, __shfl_down(m, off));
        m = __shfl(m, 0);
        float e1 = __expf(v1 - m);
        float e2 = has2 ? __expf(v2 - m) : 0.0f;
        float sm = e1 + e2;
        #pragma unroll
        for (int off = 32; off > 0; off >>= 1) sm += __shfl_down(sm, off);
        sm = __shfl(sm, 0);
        float inv = 1.0f / sm;
        fused[C_ + lane] = e1 * inv;
        if (has2) fused[C_ + lane + 64] = e2 * inv;
    }
    __syncthreads();

    // 16 expert dots: wave w owns experts 4w..4w+3, computed concurrently
    {
        const int e0 = wav * 4;
        const float* w0 = Wm + (size_t)(e0 + 0) * FAN;
        const float* w1 = Wm + (size_t)(e0 + 1) * FAN;
        const float* w2 = Wm + (size_t)(e0 + 2) * FAN;
        const float* w3 = Wm + (size_t)(e0 + 3) * FAN;
        float acc0 = 0.0f, acc1 = 0.0f, acc2 = 0.0f, acc3 = 0.0f;
        for (int j = lane; j < FAN; j += 64) {
            float f = fused[j];
            acc0 += f * w0[j];
            acc1 += f * w1[j];
            acc2 += f * w2[j];
            acc3 += f * w3[j];
        }
        #pragma unroll
        for (int off = 32; off > 0; off >>= 1) {
            acc0 += __shfl_down(acc0, off);
            acc1 += __shfl_down(acc1, off);
            acc2 += __shfl_down(acc2, off);
            acc3 += __shfl_down(acc3, off);
        }
        if (lane == 0) {
            float l0 = acc0 + bias[e0 + 0];
            float l1 = acc1 + bias[e0 + 1];
            float l2 = acc2 + bias[e0 + 2];
            float l3 = acc3 + bias[e0 + 3];
            logits_s[e0 + 0] = l0;  out[b * E_ + e0 + 0] = l0;  // router_logits @0
            logits_s[e0 + 1] = l1;  out[b * E_ + e0 + 1] = l1;
            logits_s[e0 + 2] = l2;  out[b * E_ + e0 + 2] = l2;
            logits_s[e0 + 3] = l3;  out[b * E_ + e0 + 3] = l3;
        }
    }
    __syncthreads();

    // top-2 (strict > keeps lowest index on ties, matching lax.top_k)
    if (tid == 0) {
        float m1 = -INFINITY, m2 = -INFINITY;
        int i1 = 0, i2 = 0;
        #pragma unroll
        for (int e = 0; e < E_; ++e) {
            float v = logits_s[e];
            if (v > m1) { m2 = m1; i2 = i1; m1 = v; i1 = e; }
            else if (v > m2) { m2 = v; i2 = e; }
        }
        float r = expf(m2 - m1);
        float w0 = 1.0f / (1.0f + r);
        float w1 = r * w0;
        out[1024 + b * K_ + 0] = w0;              // router_weights [B,K] @ 1024
        out[1024 + b * K_ + 1] = w1;
        out[1152 + b * K_ + 0] = (float)i1;       // selected_experts [B,K] @ 1152
        out[1152 + b * K_ + 1] = (float)i2;
        sel_s[0] = i1; sel_s[1] = i2;
    }
    __syncthreads();

    // expert_mask [E,K,B] @ 1280 : flat e*K*B + k*B + b
    if (tid < E_ * K_) {
        int e = tid >> 1;
        int k = tid & 1;
        out[1280 + e * (K_ * B_) + k * B_ + b] = (sel_s[k] == e) ? 1.0f : 0.0f;
    }
}

extern "C" void kernel_launch(void* const* d_in, const int* in_sizes, int n_in,
                              void* d_out, int out_size, void* d_ws, size_t ws_size,
                              hipStream_t stream) {
    const float* hidden   = (const float*)d_in[0];  // [64,768,32,32]
    const float* task_cls = (const float*)d_in[1];  // [64,100]
    const float* Wm       = (const float*)d_in[2];  // [16,868]
    const float* bias     = (const float*)d_in[3];  // [16]
    float* out = (float*)d_out;
    float* pooled = (float*)d_ws;                   // B*C floats = 192 KiB

    // 49152 rows, 2 rows per wave, 4 waves per block -> 6144 blocks
    pool_kernel<<<6144, 256, 0, stream>>>(hidden, pooled);
    router_kernel<<<B_, 256, 0, stream>>>(pooled, task_cls, Wm, bias, out);
}